// Round 1
// baseline (478.555 us; speedup 1.0000x reference)
//
#include <hip/hip_runtime.h>
#include <math.h>

#define N_NODES 50000
#define N_EDGES 800000
// dims: IN=16, OUT=16, EF=16, H=4, HD=32, DGAT=128

// ---------------- CSR build ----------------
__global__ void count_kernel(const int* __restrict__ dst, int* __restrict__ counts) {
    int e = blockIdx.x * 256 + threadIdx.x;
    if (e < N_EDGES) atomicAdd(&counts[dst[e]], 1);
}

__global__ void scan_kernel(const int* __restrict__ counts, int* __restrict__ offsets) {
    __shared__ int sdata[1024];
    int tid = threadIdx.x;
    const int chunk = (N_NODES + 1023) / 1024;  // 49
    int beg = tid * chunk;
    int end = min(beg + chunk, N_NODES);
    int s = 0;
    for (int j = beg; j < end; ++j) s += counts[j];
    sdata[tid] = s;
    __syncthreads();
    for (int d = 1; d < 1024; d <<= 1) {
        int v = (tid >= d) ? sdata[tid - d] : 0;
        __syncthreads();
        sdata[tid] += v;
        __syncthreads();
    }
    int base = (tid == 0) ? 0 : sdata[tid - 1];
    for (int j = beg; j < end; ++j) { offsets[j] = base; base += counts[j]; }
    if (tid == 0) offsets[N_NODES] = sdata[1023];
}

__global__ void scatter_kernel(const int* __restrict__ dst, const int* __restrict__ offsets,
                               int* __restrict__ cursor, int* __restrict__ csr_eid) {
    int e = blockIdx.x * 256 + threadIdx.x;
    if (e < N_EDGES) {
        int d = dst[e];
        int pos = offsets[d] + atomicAdd(&cursor[d], 1);
        csr_eid[pos] = e;
    }
}

// ---------------- NNConv per-edge message ----------------
// msg[e][o] = sum_i x[src[e]][i] * (b_nn[i*16+o] + sum_f ea[e][f]*W_nn[f][i*16+o])
// One thread per edge; W_nn/b_nn indexed by uniform/unrolled indices -> scalar loads.
__global__ void msg_kernel(const float* __restrict__ x, const int* __restrict__ src,
                           const float* __restrict__ ea, const float* __restrict__ Wnn,
                           const float* __restrict__ bnn, float* __restrict__ msg) {
    int e = blockIdx.x * 256 + threadIdx.x;
    if (e >= N_EDGES) return;
    int s = src[e];
    float xr[16], er[16];
    const float4* xp = (const float4*)(x + (size_t)s * 16);
    const float4* ep = (const float4*)(ea + (size_t)e * 16);
#pragma unroll
    for (int q = 0; q < 4; ++q) {
        float4 xv = xp[q];
        xr[4 * q + 0] = xv.x; xr[4 * q + 1] = xv.y; xr[4 * q + 2] = xv.z; xr[4 * q + 3] = xv.w;
        float4 ev = ep[q];
        er[4 * q + 0] = ev.x; er[4 * q + 1] = ev.y; er[4 * q + 2] = ev.z; er[4 * q + 3] = ev.w;
    }
    float m[16];
#pragma unroll
    for (int o = 0; o < 16; ++o) m[o] = 0.f;
    for (int f = 0; f < 16; ++f) {
        const float* Wf = Wnn + f * 256;
        float ef = er[f];
#pragma unroll
        for (int i = 0; i < 16; ++i) {
            float c = ef * xr[i];
#pragma unroll
            for (int o = 0; o < 16; ++o) m[o] = fmaf(c, Wf[i * 16 + o], m[o]);
        }
    }
    // b_nn contribution
#pragma unroll
    for (int i = 0; i < 16; ++i) {
        float c = xr[i];
#pragma unroll
        for (int o = 0; o < 16; ++o) m[o] = fmaf(c, bnn[i * 16 + o], m[o]);
    }
    float4* mp = (float4*)(msg + (size_t)e * 16);
#pragma unroll
    for (int q = 0; q < 4; ++q)
        mp[q] = make_float4(m[4 * q + 0], m[4 * q + 1], m[4 * q + 2], m[4 * q + 3]);
}

// ---------------- NNConv aggregate + root + relu ----------------
// 16 lanes per node (lane = output dim o)
__global__ void aggregate_kernel(const float* __restrict__ msg, const int* __restrict__ offsets,
                                 const int* __restrict__ csr_eid, const float* __restrict__ x,
                                 const float* __restrict__ Wroot, const float* __restrict__ becc,
                                 float* __restrict__ h) {
    int t = blockIdx.x * 256 + threadIdx.x;
    int n = t >> 4;
    int o = t & 15;
    if (n >= N_NODES) return;
    int beg = offsets[n], end = offsets[n + 1];
    float acc = 0.f;
    for (int j = beg; j < end; ++j) {
        int eid = csr_eid[j];
        acc += msg[(size_t)eid * 16 + o];
    }
    float r = becc[o];
#pragma unroll
    for (int i = 0; i < 16; ++i) r = fmaf(x[(size_t)n * 16 + i], Wroot[i * 16 + o], r);
    h[(size_t)n * 16 + o] = fmaxf(acc + r, 0.f);
}

// ---------------- GAT projection z = h @ W_gat, plus e_src/e_dst ----------------
// one node per block, 128 threads (one per output dim)
__global__ void z_kernel(const float* __restrict__ h, const float* __restrict__ Wgat,
                         const float* __restrict__ asrc, const float* __restrict__ adst,
                         float* __restrict__ z, float* __restrict__ es, float* __restrict__ ed) {
    int n = blockIdx.x;
    int d = threadIdx.x;  // 0..127
    float acc = 0.f;
#pragma unroll
    for (int i = 0; i < 16; ++i) acc = fmaf(h[(size_t)n * 16 + i], Wgat[i * 128 + d], acc);
    z[(size_t)n * 128 + d] = acc;
    float ps = acc * asrc[d];
    float pd = acc * adst[d];
    // reduce within 32-lane head groups
    for (int k = 16; k > 0; k >>= 1) {
        ps += __shfl_down(ps, k, 32);
        pd += __shfl_down(pd, k, 32);
    }
    if ((d & 31) == 0) {
        int head = d >> 5;
        es[(size_t)n * 4 + head] = ps;
        ed[(size_t)n * 4 + head] = pd;
    }
}

// ---------------- GAT aggregation + bias + relu + final fc ----------------
// one wave (64 lanes) per node; lane holds dims 2*lane, 2*lane+1; head = lane>>4
__global__ void gat_kernel(const float* __restrict__ z, const float* __restrict__ es,
                           const float* __restrict__ ed, const int* __restrict__ srcArr,
                           const int* __restrict__ offsets, const int* __restrict__ csr_eid,
                           const float* __restrict__ bgat, const float* __restrict__ Wfc,
                           const float* __restrict__ bfc, float* __restrict__ out) {
    int wid = threadIdx.x >> 6;
    int lane = threadIdx.x & 63;
    int n = blockIdx.x * 4 + wid;
    if (n >= N_NODES) return;
    int head = lane >> 4;
    float edh = ed[(size_t)n * 4 + head];
    int beg = offsets[n], end = offsets[n + 1];
    float m = -INFINITY, den = 0.f, a0 = 0.f, a1 = 0.f;
    for (int j = beg; j < end; ++j) {
        int eid = csr_eid[j];
        int s = srcArr[eid];
        float l = es[(size_t)s * 4 + head] + edh;
        l = (l > 0.f) ? l : 0.2f * l;
        if (l > m) {
            float f = __expf(m - l);  // m = -inf on first edge -> f = 0
            den *= f; a0 *= f; a1 *= f;
            m = l;
        }
        float w = __expf(l - m);
        den += w;
        float2 zv = *(const float2*)(z + (size_t)s * 128 + 2 * lane);
        a0 = fmaf(w, zv.x, a0);
        a1 = fmaf(w, zv.y, a1);
    }
    float inv = 1.f / (den + 1e-16f);
    float2 bg = *(const float2*)(bgat + 2 * lane);
    float g0 = fmaxf(fmaf(a0, inv, bg.x), 0.f);
    float g1 = fmaxf(fmaf(a1, inv, bg.y), 0.f);
    float2 wf = *(const float2*)(Wfc + 2 * lane);
    float p = g0 * wf.x + g1 * wf.y;
    for (int k = 32; k > 0; k >>= 1) p += __shfl_down(p, k, 64);
    if (lane == 0) out[n] = p + bfc[0];
}

extern "C" void kernel_launch(void* const* d_in, const int* in_sizes, int n_in,
                              void* d_out, int out_size, void* d_ws, size_t ws_size,
                              hipStream_t stream) {
    const float* x     = (const float*)d_in[0];
    const int*   eidx  = (const int*)d_in[1];
    const float* ea    = (const float*)d_in[2];
    const float* Wnn   = (const float*)d_in[3];
    const float* bnn   = (const float*)d_in[4];
    const float* Wroot = (const float*)d_in[5];
    const float* becc  = (const float*)d_in[6];
    const float* Wgat  = (const float*)d_in[7];
    const float* asrc  = (const float*)d_in[8];
    const float* adst  = (const float*)d_in[9];
    const float* bgat  = (const float*)d_in[10];
    const float* Wfc   = (const float*)d_in[11];
    const float* bfc   = (const float*)d_in[12];
    const int* src = eidx;
    const int* dst = eidx + N_EDGES;
    float* out = (float*)d_out;

    char* ws = (char*)d_ws;
    size_t off = 0;
    auto alloc = [&](size_t bytes) {
        void* p = ws + off;
        off += (bytes + 255) & ~(size_t)255;
        return p;
    };
    int*   counts  = (int*)alloc((size_t)N_NODES * 4);
    int*   cursor  = (int*)alloc((size_t)N_NODES * 4);
    int*   offsets = (int*)alloc((size_t)(N_NODES + 1) * 4);
    int*   csr     = (int*)alloc((size_t)N_EDGES * 4);
    float* msg     = (float*)alloc((size_t)N_EDGES * 16 * 4);
    float* h       = (float*)alloc((size_t)N_NODES * 16 * 4);
    float* z       = (float*)alloc((size_t)N_NODES * 128 * 4);
    float* es      = (float*)alloc((size_t)N_NODES * 4 * 4);
    float* ed      = (float*)alloc((size_t)N_NODES * 4 * 4);

    hipMemsetAsync(counts, 0, (size_t)N_NODES * 4, stream);
    hipMemsetAsync(cursor, 0, (size_t)N_NODES * 4, stream);

    int eb = (N_EDGES + 255) / 256;
    count_kernel<<<eb, 256, 0, stream>>>(dst, counts);
    scan_kernel<<<1, 1024, 0, stream>>>(counts, offsets);
    scatter_kernel<<<eb, 256, 0, stream>>>(dst, offsets, cursor, csr);
    msg_kernel<<<eb, 256, 0, stream>>>(x, src, ea, Wnn, bnn, msg);
    aggregate_kernel<<<(N_NODES * 16 + 255) / 256, 256, 0, stream>>>(msg, offsets, csr, x, Wroot, becc, h);
    z_kernel<<<N_NODES, 128, 0, stream>>>(h, Wgat, asrc, adst, z, es, ed);
    gat_kernel<<<(N_NODES + 3) / 4, 256, 0, stream>>>(z, es, ed, src, offsets, csr, bgat, Wfc, bfc, out);
}

// Round 2
// 378.852 us; speedup vs baseline: 1.2632x; 1.2632x over previous
//
#include <hip/hip_runtime.h>
#include <math.h>

#define N_NODES 50000
#define N_EDGES 800000
// dims: IN=16, OUT=16, EF=16, H=4, HD=32, DGAT=128

// ---------------- CSR build ----------------
__global__ void count_kernel(const int* __restrict__ dst, int* __restrict__ counts) {
    int e = blockIdx.x * 256 + threadIdx.x;
    if (e < N_EDGES) atomicAdd(&counts[dst[e]], 1);
}

__global__ void scan_kernel(const int* __restrict__ counts, int* __restrict__ offsets) {
    __shared__ int sdata[1024];
    int tid = threadIdx.x;
    const int chunk = (N_NODES + 1023) / 1024;  // 49
    int beg = tid * chunk;
    int end = min(beg + chunk, N_NODES);
    int s = 0;
    for (int j = beg; j < end; ++j) s += counts[j];
    sdata[tid] = s;
    __syncthreads();
    for (int d = 1; d < 1024; d <<= 1) {
        int v = (tid >= d) ? sdata[tid - d] : 0;
        __syncthreads();
        sdata[tid] += v;
        __syncthreads();
    }
    int base = (tid == 0) ? 0 : sdata[tid - 1];
    for (int j = beg; j < end; ++j) { offsets[j] = base; base += counts[j]; }
    if (tid == 0) offsets[N_NODES] = sdata[1023];
}

__global__ void scatter_kernel(const int* __restrict__ src, const int* __restrict__ dst,
                               const int* __restrict__ offsets,
                               int* __restrict__ cursor, int* __restrict__ csr_eid,
                               int* __restrict__ csr_src) {
    int e = blockIdx.x * 256 + threadIdx.x;
    if (e < N_EDGES) {
        int d = dst[e];
        int pos = offsets[d] + atomicAdd(&cursor[d], 1);
        csr_eid[pos] = e;
        csr_src[pos] = src[e];
    }
}

// ---------------- NNConv per-edge message, keyed by CSR position ----------------
// msg[j][o] = sum_i x[s][i] * (b_nn[i*16+o] + sum_f ea[eid][f]*W_nn[f][i*16+o])
// Random ea/x gathers hidden under 4096 FMAs/thread; msg written linearly in CSR order.
__global__ void msg_kernel(const float* __restrict__ x, const int* __restrict__ csr_eid,
                           const int* __restrict__ csr_src,
                           const float* __restrict__ ea, const float* __restrict__ Wnn,
                           const float* __restrict__ bnn, float* __restrict__ msg) {
    int j = blockIdx.x * 256 + threadIdx.x;
    if (j >= N_EDGES) return;
    int eid = csr_eid[j];
    int s = csr_src[j];
    float xr[16], er[16];
    const float4* xp = (const float4*)(x + (size_t)s * 16);
    const float4* ep = (const float4*)(ea + (size_t)eid * 16);
#pragma unroll
    for (int q = 0; q < 4; ++q) {
        float4 xv = xp[q];
        xr[4 * q + 0] = xv.x; xr[4 * q + 1] = xv.y; xr[4 * q + 2] = xv.z; xr[4 * q + 3] = xv.w;
        float4 ev = ep[q];
        er[4 * q + 0] = ev.x; er[4 * q + 1] = ev.y; er[4 * q + 2] = ev.z; er[4 * q + 3] = ev.w;
    }
    float m[16];
#pragma unroll
    for (int o = 0; o < 16; ++o) m[o] = 0.f;
    for (int f = 0; f < 16; ++f) {
        const float* Wf = Wnn + f * 256;
        float ef = er[f];
#pragma unroll
        for (int i = 0; i < 16; ++i) {
            float c = ef * xr[i];
#pragma unroll
            for (int o = 0; o < 16; ++o) m[o] = fmaf(c, Wf[i * 16 + o], m[o]);
        }
    }
#pragma unroll
    for (int i = 0; i < 16; ++i) {
        float c = xr[i];
#pragma unroll
        for (int o = 0; o < 16; ++o) m[o] = fmaf(c, bnn[i * 16 + o], m[o]);
    }
    float4* mp = (float4*)(msg + (size_t)j * 16);
#pragma unroll
    for (int q = 0; q < 4; ++q)
        mp[q] = make_float4(m[4 * q + 0], m[4 * q + 1], m[4 * q + 2], m[4 * q + 3]);
}

// ---------------- NNConv aggregate + root + relu ----------------
// 16 lanes per node; msg is in CSR order -> purely streaming contiguous reads.
__global__ void aggregate_kernel(const float* __restrict__ msg, const int* __restrict__ offsets,
                                 const float* __restrict__ x,
                                 const float* __restrict__ Wroot, const float* __restrict__ becc,
                                 float* __restrict__ h) {
    int t = blockIdx.x * 256 + threadIdx.x;
    int n = t >> 4;
    int o = t & 15;
    if (n >= N_NODES) return;
    int beg = offsets[n], end = offsets[n + 1];
    float acc = 0.f;
    int j = beg;
#pragma unroll 4
    for (; j + 4 <= end; j += 4) {
        acc += msg[(size_t)(j + 0) * 16 + o];
        acc += msg[(size_t)(j + 1) * 16 + o];
        acc += msg[(size_t)(j + 2) * 16 + o];
        acc += msg[(size_t)(j + 3) * 16 + o];
    }
    for (; j < end; ++j) acc += msg[(size_t)j * 16 + o];
    float r = becc[o];
#pragma unroll
    for (int i = 0; i < 16; ++i) r = fmaf(x[(size_t)n * 16 + i], Wroot[i * 16 + o], r);
    h[(size_t)n * 16 + o] = fmaxf(acc + r, 0.f);
}

// ---------------- GAT projection z = h @ W_gat, plus e_src/e_dst ----------------
// 2 nodes per 256-block; thread = (node, dim)
__global__ void z_kernel(const float* __restrict__ h, const float* __restrict__ Wgat,
                         const float* __restrict__ asrc, const float* __restrict__ adst,
                         float* __restrict__ z, float* __restrict__ es, float* __restrict__ ed) {
    int n = blockIdx.x * 2 + (threadIdx.x >> 7);
    int d = threadIdx.x & 127;
    if (n >= N_NODES) return;
    float acc = 0.f;
#pragma unroll
    for (int i = 0; i < 16; ++i) acc = fmaf(h[(size_t)n * 16 + i], Wgat[i * 128 + d], acc);
    z[(size_t)n * 128 + d] = acc;
    float ps = acc * asrc[d];
    float pd = acc * adst[d];
    for (int k = 16; k > 0; k >>= 1) {
        ps += __shfl_down(ps, k, 32);
        pd += __shfl_down(pd, k, 32);
    }
    if ((d & 31) == 0) {
        int head = d >> 5;
        es[(size_t)n * 4 + head] = ps;
        ed[(size_t)n * 4 + head] = pd;
    }
}

// ---------------- GAT aggregation + bias + relu + final fc ----------------
// one wave per node; lane holds dims 2*lane, 2*lane+1; head = lane>>4.
// No max-subtraction (softmax is shift-invariant; logits are O(few), exp safe).
// Up to 64 src indices preloaded coalesced, broadcast via shuffle -> loop
// iterations independent and pipelineable.
__global__ void gat_kernel(const float* __restrict__ z, const float* __restrict__ es,
                           const float* __restrict__ ed, const int* __restrict__ csr_src,
                           const int* __restrict__ offsets,
                           const float* __restrict__ bgat, const float* __restrict__ Wfc,
                           const float* __restrict__ bfc, float* __restrict__ out) {
    int wid = threadIdx.x >> 6;
    int lane = threadIdx.x & 63;
    int n = blockIdx.x * 4 + wid;
    if (n >= N_NODES) return;
    int head = lane >> 4;
    float edh = ed[(size_t)n * 4 + head];
    int beg = offsets[n], end = offsets[n + 1];
    int deg = end - beg;
    float den = 0.f, a0 = 0.f, a1 = 0.f;
    int s_l = (lane < deg) ? csr_src[beg + lane] : 0;
    int m64 = min(deg, 64);
#pragma unroll 4
    for (int el = 0; el < m64; ++el) {
        int s = __shfl(s_l, el, 64);
        float l = es[(size_t)s * 4 + head] + edh;
        l = (l > 0.f) ? l : 0.2f * l;
        float w = __expf(l);
        den += w;
        float2 zv = *(const float2*)(z + (size_t)s * 128 + 2 * lane);
        a0 = fmaf(w, zv.x, a0);
        a1 = fmaf(w, zv.y, a1);
    }
    for (int j = beg + 64; j < end; ++j) {  // rare: deg > 64
        int s = csr_src[j];
        float l = es[(size_t)s * 4 + head] + edh;
        l = (l > 0.f) ? l : 0.2f * l;
        float w = __expf(l);
        den += w;
        float2 zv = *(const float2*)(z + (size_t)s * 128 + 2 * lane);
        a0 = fmaf(w, zv.x, a0);
        a1 = fmaf(w, zv.y, a1);
    }
    float inv = 1.f / (den + 1e-16f);
    float2 bg = *(const float2*)(bgat + 2 * lane);
    float g0 = fmaxf(fmaf(a0, inv, bg.x), 0.f);
    float g1 = fmaxf(fmaf(a1, inv, bg.y), 0.f);
    float2 wf = *(const float2*)(Wfc + 2 * lane);
    float p = g0 * wf.x + g1 * wf.y;
    for (int k = 32; k > 0; k >>= 1) p += __shfl_down(p, k, 64);
    if (lane == 0) out[n] = p + bfc[0];
}

extern "C" void kernel_launch(void* const* d_in, const int* in_sizes, int n_in,
                              void* d_out, int out_size, void* d_ws, size_t ws_size,
                              hipStream_t stream) {
    const float* x     = (const float*)d_in[0];
    const int*   eidx  = (const int*)d_in[1];
    const float* ea    = (const float*)d_in[2];
    const float* Wnn   = (const float*)d_in[3];
    const float* bnn   = (const float*)d_in[4];
    const float* Wroot = (const float*)d_in[5];
    const float* becc  = (const float*)d_in[6];
    const float* Wgat  = (const float*)d_in[7];
    const float* asrc  = (const float*)d_in[8];
    const float* adst  = (const float*)d_in[9];
    const float* bgat  = (const float*)d_in[10];
    const float* Wfc   = (const float*)d_in[11];
    const float* bfc   = (const float*)d_in[12];
    const int* src = eidx;
    const int* dst = eidx + N_EDGES;
    float* out = (float*)d_out;

    char* ws = (char*)d_ws;
    size_t off = 0;
    auto alloc = [&](size_t bytes) {
        void* p = ws + off;
        off += (bytes + 255) & ~(size_t)255;
        return p;
    };
    int*   counts  = (int*)alloc((size_t)N_NODES * 4);
    int*   cursor  = (int*)alloc((size_t)N_NODES * 4);
    int*   offsets = (int*)alloc((size_t)(N_NODES + 1) * 4);
    int*   csr_eid = (int*)alloc((size_t)N_EDGES * 4);
    int*   csr_src = (int*)alloc((size_t)N_EDGES * 4);
    float* msg     = (float*)alloc((size_t)N_EDGES * 16 * 4);
    float* h       = (float*)alloc((size_t)N_NODES * 16 * 4);
    float* z       = (float*)alloc((size_t)N_NODES * 128 * 4);
    float* es      = (float*)alloc((size_t)N_NODES * 4 * 4);
    float* ed      = (float*)alloc((size_t)N_NODES * 4 * 4);

    hipMemsetAsync(counts, 0, (size_t)N_NODES * 4, stream);
    hipMemsetAsync(cursor, 0, (size_t)N_NODES * 4, stream);

    int eb = (N_EDGES + 255) / 256;
    count_kernel<<<eb, 256, 0, stream>>>(dst, counts);
    scan_kernel<<<1, 1024, 0, stream>>>(counts, offsets);
    scatter_kernel<<<eb, 256, 0, stream>>>(src, dst, offsets, cursor, csr_eid, csr_src);
    msg_kernel<<<eb, 256, 0, stream>>>(x, csr_eid, csr_src, ea, Wnn, bnn, msg);
    aggregate_kernel<<<(N_NODES * 16 + 255) / 256, 256, 0, stream>>>(msg, offsets, x, Wroot, becc, h);
    z_kernel<<<(N_NODES + 1) / 2, 256, 0, stream>>>(h, Wgat, asrc, adst, z, es, ed);
    gat_kernel<<<(N_NODES + 3) / 4, 256, 0, stream>>>(z, es, ed, csr_src, offsets, bgat, Wfc, bfc, out);
}

// Round 3
// 336.166 us; speedup vs baseline: 1.4236x; 1.1270x over previous
//
#include <hip/hip_runtime.h>
#include <hip/hip_bf16.h>
#include <math.h>

#define N_NODES 50000
#define N_EDGES 800000
// dims: IN=16, OUT=16, EF=16, H=4, HD=32, DGAT=128

typedef __attribute__((ext_vector_type(8))) short short8v;   // bf16x8 frag (4 VGPR)
typedef __attribute__((ext_vector_type(4))) float f32x4;     // C/D frag

__device__ inline short f2bf(float f) {
    __hip_bfloat16 h = __float2bfloat16(f);
    return __builtin_bit_cast(short, h);
}

// ---------------- CSR build ----------------
__global__ void count_kernel(const int* __restrict__ dst, int* __restrict__ counts) {
    int e = blockIdx.x * 256 + threadIdx.x;
    if (e < N_EDGES) atomicAdd(&counts[dst[e]], 1);
}

__global__ void scan_kernel(const int* __restrict__ counts, int* __restrict__ offsets) {
    __shared__ int sdata[1024];
    int tid = threadIdx.x;
    const int chunk = (N_NODES + 1023) / 1024;
    int beg = tid * chunk;
    int end = min(beg + chunk, N_NODES);
    int s = 0;
    for (int j = beg; j < end; ++j) s += counts[j];
    sdata[tid] = s;
    __syncthreads();
    for (int d = 1; d < 1024; d <<= 1) {
        int v = (tid >= d) ? sdata[tid - d] : 0;
        __syncthreads();
        sdata[tid] += v;
        __syncthreads();
    }
    int base = (tid == 0) ? 0 : sdata[tid - 1];
    for (int j = beg; j < end; ++j) { offsets[j] = base; base += counts[j]; }
    if (tid == 0) offsets[N_NODES] = sdata[1023];
}

__global__ void scatter_kernel(const int* __restrict__ src, const int* __restrict__ dst,
                               const int* __restrict__ offsets,
                               int* __restrict__ cursor, int* __restrict__ csr_eid,
                               int* __restrict__ csr_src) {
    int e = blockIdx.x * 256 + threadIdx.x;
    if (e < N_EDGES) {
        int d = dst[e];
        int pos = offsets[d] + atomicAdd(&cursor[d], 1);
        csr_eid[pos] = e;
        csr_src[pos] = src[e];
    }
}

// ---------------- Fused ECC: NNConv(MFMA) + root + relu + GAT projection ----------------
// One wave per node-chunk. Per node: C(16x16) accumulates over edge tiles via
// mfma_f32_16x16x32_bf16 with A[row=edge][k=f*16+i] = ea[eid][f]*x[src][i] built on the
// fly (K extended to 288: rows 256..271 carry x for the b_nn bias term, 272..287 zero).
// B = Wnn viewed as [256][16] (+ bnn rows), per-lane frags preloaded once.
// Then: segment-sum = row-sum of C, + x@W_root + b, relu -> h (in-wave only),
// z = h@W_gat (2 dims/lane), es/ed via 32-lane group reduction.
#define ECC_BLOCKS 1024
#define ECC_WAVES (ECC_BLOCKS * 4)
__global__ __launch_bounds__(256) void ecc_kernel(
    const float* __restrict__ x, const int* __restrict__ csr_src,
    const int* __restrict__ csr_eid, const int* __restrict__ offsets,
    const float* __restrict__ ea, const float* __restrict__ Wnn,
    const float* __restrict__ bnn, const float* __restrict__ Wroot,
    const float* __restrict__ becc, const float* __restrict__ Wgat,
    const float* __restrict__ asrc, const float* __restrict__ adst,
    float* __restrict__ z, float* __restrict__ es, float* __restrict__ ed)
{
    __shared__ float xt[4][16 * 20];   // per-wave x tile, rows padded to 20 words
    __shared__ float et[4][16 * 20];   // per-wave ea tile
    __shared__ float hx[4][16];        // per-wave h exchange

    const int wid  = threadIdx.x >> 6;
    const int lane = threadIdx.x & 63;
    const int row  = lane & 15;        // edge-in-tile (A row / C col index domain)
    const int g    = lane >> 4;        // k-block group
    const int col  = row;              // B col = C col = output dim o

    // ---- prologue: per-lane B fragments (once per wave) ----
    short8v bfrag[9];
#pragma unroll
    for (int kk = 0; kk < 9; ++kk) {
#pragma unroll
        for (int j = 0; j < 8; ++j) {
            int k = kk * 32 + g * 8 + j;
            float v = 0.f;
            if (k < 256) v = Wnn[k * 16 + col];
            else if (k < 272) v = bnn[(k - 256) * 16 + col];
            bfrag[kk][j] = f2bf(v);
        }
    }
    // W_gat columns for this lane (z dims: lane and lane+64)
    float wg0[16], wg1[16];
#pragma unroll
    for (int i = 0; i < 16; ++i) {
        wg0[i] = Wgat[i * 128 + lane];
        wg1[i] = Wgat[i * 128 + 64 + lane];
    }
    const float as0 = asrc[lane], as1 = asrc[lane + 64];
    const float ad0 = adst[lane], ad1 = adst[lane + 64];

    const int wgid = blockIdx.x * 4 + wid;
    const int per = (N_NODES + ECC_WAVES - 1) / ECC_WAVES;
    const int n0 = wgid * per;
    const int n1 = min(n0 + per, N_NODES);

    for (int n = n0; n < n1; ++n) {
        const int beg = offsets[n], end = offsets[n + 1];
        f32x4 c = {0.f, 0.f, 0.f, 0.f};

        for (int t = beg; t < end; t += 16) {
            const int rem = end - t;
            const bool valid = row < rem;
            int sidx = 0, eidx = 0;
            if (valid) { sidx = csr_src[t + row]; eidx = csr_eid[t + row]; }
            float4 zero4 = make_float4(0.f, 0.f, 0.f, 0.f);
            float4 xv = valid ? *(const float4*)(x  + (size_t)sidx * 16 + g * 4) : zero4;
            float4 ev = valid ? *(const float4*)(ea + (size_t)eidx * 16 + g * 4) : zero4;
            *(float4*)&xt[wid][row * 20 + g * 4] = xv;
            *(float4*)&et[wid][row * 20 + g * 4] = ev;
            asm volatile("s_waitcnt lgkmcnt(0)" ::: "memory");

            // lane's x slice: x_row[(g&1)*8 .. +7]
            float4 xa = *(const float4*)&xt[wid][row * 20 + (g & 1) * 8];
            float4 xb = *(const float4*)&xt[wid][row * 20 + (g & 1) * 8 + 4];
            float x8r[8] = {xa.x, xa.y, xa.z, xa.w, xb.x, xb.y, xb.z, xb.w};

#pragma unroll
            for (int kk = 0; kk < 8; ++kk) {
                float ef = et[wid][row * 20 + 2 * kk + (g >> 1)];
                short8v a8;
#pragma unroll
                for (int j = 0; j < 8; ++j) a8[j] = f2bf(ef * x8r[j]);
                c = __builtin_amdgcn_mfma_f32_16x16x32_bf16(a8, bfrag[kk], c, 0, 0, 0);
            }
            // bias rows (k 256..287): A = x for g<2, 0 for g>=2
            {
                short8v a8;
#pragma unroll
                for (int j = 0; j < 8; ++j) a8[j] = f2bf((g < 2) ? x8r[j] : 0.f);
                c = __builtin_amdgcn_mfma_f32_16x16x32_bf16(a8, bfrag[8], c, 0, 0, 0);
            }
        }

        // segment-sum = sum of C rows: lane holds rows g*4..g*4+3 of col
        float s = c[0] + c[1] + c[2] + c[3];
        s += __shfl_xor(s, 16, 64);
        s += __shfl_xor(s, 32, 64);     // all lanes: agg[col]

        // root weight + bias + relu
        float r = becc[col];
#pragma unroll
        for (int i = 0; i < 16; ++i)
            r = fmaf(x[(size_t)n * 16 + i], Wroot[i * 16 + col], r);
        float h = fmaxf(s + r, 0.f);

        // exchange h across lanes
        if (g == 0) hx[wid][col] = h;
        asm volatile("s_waitcnt lgkmcnt(0)" ::: "memory");

        // z = h @ Wgat (dims lane, lane+64)
        float z0 = 0.f, z1 = 0.f;
#pragma unroll
        for (int i = 0; i < 16; ++i) {
            float hv = hx[wid][i];
            z0 = fmaf(hv, wg0[i], z0);
            z1 = fmaf(hv, wg1[i], z1);
        }
        z[(size_t)n * 128 + lane] = z0;
        z[(size_t)n * 128 + 64 + lane] = z1;

        // es/ed: per-head dot products, reduce within 32-lane groups
        float p0s = z0 * as0, p1s = z1 * as1;
        float p0d = z0 * ad0, p1d = z1 * ad1;
#pragma unroll
        for (int k = 1; k <= 16; k <<= 1) {
            p0s += __shfl_xor(p0s, k, 64);
            p1s += __shfl_xor(p1s, k, 64);
            p0d += __shfl_xor(p0d, k, 64);
            p1d += __shfl_xor(p1d, k, 64);
        }
        if ((lane & 31) == 0) {
            int h0 = lane >> 5;          // 0 or 1
            es[(size_t)n * 4 + h0]     = p0s;
            es[(size_t)n * 4 + h0 + 2] = p1s;
            ed[(size_t)n * 4 + h0]     = p0d;
            ed[(size_t)n * 4 + h0 + 2] = p1d;
        }
    }
}

// ---------------- GAT aggregation + bias + relu + final fc ----------------
__global__ void gat_kernel(const float* __restrict__ z, const float* __restrict__ es,
                           const float* __restrict__ ed, const int* __restrict__ csr_src,
                           const int* __restrict__ offsets,
                           const float* __restrict__ bgat, const float* __restrict__ Wfc,
                           const float* __restrict__ bfc, float* __restrict__ out) {
    int wid = threadIdx.x >> 6;
    int lane = threadIdx.x & 63;
    int n = blockIdx.x * 4 + wid;
    if (n >= N_NODES) return;
    int head = lane >> 4;
    float edh = ed[(size_t)n * 4 + head];
    int beg = offsets[n], end = offsets[n + 1];
    int deg = end - beg;
    float den = 0.f, a0 = 0.f, a1 = 0.f;
    int s_l = (lane < deg) ? csr_src[beg + lane] : 0;
    int m64 = min(deg, 64);
#pragma unroll 4
    for (int el = 0; el < m64; ++el) {
        int s = __shfl(s_l, el, 64);
        float l = es[(size_t)s * 4 + head] + edh;
        l = (l > 0.f) ? l : 0.2f * l;
        float w = __expf(l);
        den += w;
        float2 zv = *(const float2*)(z + (size_t)s * 128 + 2 * lane);
        a0 = fmaf(w, zv.x, a0);
        a1 = fmaf(w, zv.y, a1);
    }
    for (int j = beg + 64; j < end; ++j) {
        int s = csr_src[j];
        float l = es[(size_t)s * 4 + head] + edh;
        l = (l > 0.f) ? l : 0.2f * l;
        float w = __expf(l);
        den += w;
        float2 zv = *(const float2*)(z + (size_t)s * 128 + 2 * lane);
        a0 = fmaf(w, zv.x, a0);
        a1 = fmaf(w, zv.y, a1);
    }
    float inv = 1.f / (den + 1e-16f);
    float2 bg = *(const float2*)(bgat + 2 * lane);
    float g0 = fmaxf(fmaf(a0, inv, bg.x), 0.f);
    float g1 = fmaxf(fmaf(a1, inv, bg.y), 0.f);
    float2 wf = *(const float2*)(Wfc + 2 * lane);
    float p = g0 * wf.x + g1 * wf.y;
    for (int k = 32; k > 0; k >>= 1) p += __shfl_down(p, k, 64);
    if (lane == 0) out[n] = p + bfc[0];
}

extern "C" void kernel_launch(void* const* d_in, const int* in_sizes, int n_in,
                              void* d_out, int out_size, void* d_ws, size_t ws_size,
                              hipStream_t stream) {
    const float* x     = (const float*)d_in[0];
    const int*   eidx  = (const int*)d_in[1];
    const float* ea    = (const float*)d_in[2];
    const float* Wnn   = (const float*)d_in[3];
    const float* bnn   = (const float*)d_in[4];
    const float* Wroot = (const float*)d_in[5];
    const float* becc  = (const float*)d_in[6];
    const float* Wgat  = (const float*)d_in[7];
    const float* asrc  = (const float*)d_in[8];
    const float* adst  = (const float*)d_in[9];
    const float* bgat  = (const float*)d_in[10];
    const float* Wfc   = (const float*)d_in[11];
    const float* bfc   = (const float*)d_in[12];
    const int* src = eidx;
    const int* dst = eidx + N_EDGES;
    float* out = (float*)d_out;

    char* ws = (char*)d_ws;
    size_t off = 0;
    auto alloc = [&](size_t bytes) {
        void* p = ws + off;
        off += (bytes + 255) & ~(size_t)255;
        return p;
    };
    int*   counts  = (int*)alloc((size_t)N_NODES * 4);
    int*   cursor  = (int*)alloc((size_t)N_NODES * 4);
    int*   offsets = (int*)alloc((size_t)(N_NODES + 1) * 4);
    int*   csr_eid = (int*)alloc((size_t)N_EDGES * 4);
    int*   csr_src = (int*)alloc((size_t)N_EDGES * 4);
    float* z       = (float*)alloc((size_t)N_NODES * 128 * 4);
    float* es      = (float*)alloc((size_t)N_NODES * 4 * 4);
    float* ed      = (float*)alloc((size_t)N_NODES * 4 * 4);

    hipMemsetAsync(counts, 0, (size_t)N_NODES * 4, stream);
    hipMemsetAsync(cursor, 0, (size_t)N_NODES * 4, stream);

    int eb = (N_EDGES + 255) / 256;
    count_kernel<<<eb, 256, 0, stream>>>(dst, counts);
    scan_kernel<<<1, 1024, 0, stream>>>(counts, offsets);
    scatter_kernel<<<eb, 256, 0, stream>>>(src, dst, offsets, cursor, csr_eid, csr_src);
    ecc_kernel<<<ECC_BLOCKS, 256, 0, stream>>>(x, csr_src, csr_eid, offsets, ea, Wnn, bnn,
                                               Wroot, becc, Wgat, asrc, adst, z, es, ed);
    gat_kernel<<<(N_NODES + 3) / 4, 256, 0, stream>>>(z, es, ed, csr_src, offsets, bgat, Wfc, bfc, out);
}